// Round 1
// baseline (1423.477 us; speedup 1.0000x reference)
//
#include <hip/hip_runtime.h>
#include <hip/hip_bf16.h>

// GraphConvolution on MI355X:
//   supT = (input @ W^T + b)^T  computed directly as  W @ input^T + b[row]   (NT GEMM, bf16 MFMA)
//   out_u = deg_u  * (adj  @ sup_i)  = NT GEMM(A=adj_bf,  B=supT+8192 rows)
//   out_i = deg_i  * (adjT @ sup_u)  = NT GEMM(A=adjT_bf, B=supT)
// Workspace layout (needs >= 320 MiB):
//   [0,64Mi)    supT   2048x16384 bf16
//   [64,128Mi)  in_bf  16384x2048 bf16   -- reused by adj_bf after GEMM1
//   [128,136Mi) W_bf   2048x2048  bf16   -- dead after GEMM1 (inside adj_bf region)
//   [64,192Mi)  adj_bf 8192x8192  bf16
//   [192,320Mi) adjT   8192x8192  bf16

typedef __bf16 bf16;
typedef bf16 bf16x4 __attribute__((ext_vector_type(4)));
typedef bf16 bf16x8 __attribute__((ext_vector_type(8)));
typedef float f32x4 __attribute__((ext_vector_type(4)));

#define AS1 __attribute__((address_space(1)))
#define AS3 __attribute__((address_space(3)))

// ---------------- fp32 -> bf16 straight convert (4 elems/thread) ----------------
__global__ __launch_bounds__(256) void k_cvt(const float* __restrict__ src,
                                             bf16* __restrict__ dst) {
  long i = ((long)blockIdx.x * 256 + threadIdx.x) * 4;
  float4 v = *(const float4*)(src + i);
  bf16x4 o;
  o.x = (bf16)v.x; o.y = (bf16)v.y; o.z = (bf16)v.z; o.w = (bf16)v.w;
  *(bf16x4*)(dst + i) = o;
}

// ---------------- fp32 -> bf16 transposing convert (64x64 tiles via LDS) --------
__global__ __launch_bounds__(256) void k_transpose_cvt(const float* __restrict__ src,
                                                       bf16* __restrict__ dst, int n) {
  __shared__ float tile[64][65];
  const int bx = blockIdx.x * 64;  // source col block
  const int by = blockIdx.y * 64;  // source row block
  const int tx = threadIdx.x & 15, ty = threadIdx.x >> 4;
#pragma unroll
  for (int p = 0; p < 4; ++p) {
    float4 v = *(const float4*)(src + (long)(by + p * 16 + ty) * n + bx + tx * 4);
    tile[p * 16 + ty][tx * 4 + 0] = v.x;
    tile[p * 16 + ty][tx * 4 + 1] = v.y;
    tile[p * 16 + ty][tx * 4 + 2] = v.z;
    tile[p * 16 + ty][tx * 4 + 3] = v.w;
  }
  __syncthreads();
#pragma unroll
  for (int p = 0; p < 4; ++p) {
    bf16x4 o;
    o.x = (bf16)tile[tx * 4 + 0][p * 16 + ty];
    o.y = (bf16)tile[tx * 4 + 1][p * 16 + ty];
    o.z = (bf16)tile[tx * 4 + 2][p * 16 + ty];
    o.w = (bf16)tile[tx * 4 + 3][p * 16 + ty];
    *(bf16x4*)(dst + (long)(bx + p * 16 + ty) * n + by + tx * 4) = o;
  }
}

// ---------------- NT bf16 GEMM, m97 structure ----------------
// C[m][n] = rowscale[m] * (sum_k A[m][k]*B[n][k]) + rowbias[m]
// BM=BN=128, BK=64, 256 threads (4 waves, each 64x64 of C via 4x4 16x16x32 MFMA).
// global_load_lds width=16 staging; XOR k-chunk swizzle folded into the GLOBAL
// address (LDS dest stays lane-contiguous as the DMA requires) so ds_read_b128
// fragment reads land on distinct bank quads (2-way max = free).
template <bool OUT_BF16>
__global__ __launch_bounds__(256) void k_gemm_nt(
    const bf16* __restrict__ A, const bf16* __restrict__ B, void* __restrict__ Cout,
    int K, int lda, int ldb, int ldc,
    const float* __restrict__ rowscale, const float* __restrict__ rowbias) {
  constexpr int BK = 64;
  __shared__ __align__(16) bf16 As[128 * BK];
  __shared__ __align__(16) bf16 Bs[128 * BK];
  const int tid = threadIdx.x;
  const int wave = tid >> 6, lane = tid & 63;
  const int quad = lane >> 4, l16 = lane & 15;
  const int bm = blockIdx.y * 128, bn = blockIdx.x * 128;
  const bf16* Ab = A + (long)bm * lda;
  const bf16* Bb = B + (long)bn * ldb;
  f32x4 acc[4][4] = {};
  const int mrow = (wave & 1) * 64 + l16;  // A-fragment row (per lane)
  const int ncol = (wave >> 1) * 64 + l16; // B-fragment row (per lane)
  const int xm = l16 & 7;                  // fragment-side XOR swizzle key

  for (int k0 = 0; k0 < K; k0 += BK) {
    __syncthreads();
#pragma unroll
    for (int it = 0; it < 4; ++it) {
      const int c = it * 256 + tid;        // 16B chunk index in LDS
      const int row = c >> 3;
      const int kc = ((c & 7) ^ (row & 7)) * 8;  // swizzled k within the tile row
      __builtin_amdgcn_global_load_lds((AS1 void*)(Ab + row * lda + k0 + kc),
                                       (AS3 void*)(As + c * 8), 16, 0, 0);
      __builtin_amdgcn_global_load_lds((AS1 void*)(Bb + row * ldb + k0 + kc),
                                       (AS3 void*)(Bs + c * 8), 16, 0, 0);
    }
    __syncthreads();
#pragma unroll
    for (int ks = 0; ks < 2; ++ks) {
      const int jl = ks * 4 + quad;        // logical 16B chunk within row
      bf16x8 af[4], bfr[4];
#pragma unroll
      for (int i = 0; i < 4; ++i)
        af[i] = *(const bf16x8*)(As + (mrow + i * 16) * BK + ((jl ^ xm) << 3));
#pragma unroll
      for (int j = 0; j < 4; ++j)
        bfr[j] = *(const bf16x8*)(Bs + (ncol + j * 16) * BK + ((jl ^ xm) << 3));
#pragma unroll
      for (int i = 0; i < 4; ++i)
#pragma unroll
        for (int j = 0; j < 4; ++j)
          acc[i][j] = __builtin_amdgcn_mfma_f32_16x16x32_bf16(af[i], bfr[j], acc[i][j], 0, 0, 0);
    }
  }

  // Epilogue: C/D layout col=lane&15, row=quad*4+reg (guide §3, m89-verified).
#pragma unroll
  for (int i = 0; i < 4; ++i) {
    const int r0 = bm + (wave & 1) * 64 + i * 16 + quad * 4;
    float sc[4], bi[4];
#pragma unroll
    for (int r = 0; r < 4; ++r) {
      sc[r] = rowscale ? rowscale[r0 + r] : 1.0f;
      bi[r] = rowbias ? rowbias[r0 + r] : 0.0f;
    }
#pragma unroll
    for (int j = 0; j < 4; ++j) {
      const int col = bn + (wave >> 1) * 64 + j * 16 + l16;
#pragma unroll
      for (int r = 0; r < 4; ++r) {
        float v = acc[i][j][r] * sc[r] + bi[r];
        long idx = (long)(r0 + r) * ldc + col;
        if (OUT_BF16) ((bf16*)Cout)[idx] = (bf16)v;
        else          ((float*)Cout)[idx] = v;
      }
    }
  }
}

extern "C" void kernel_launch(void* const* d_in, const int* in_sizes, int n_in,
                              void* d_out, int out_size, void* d_ws, size_t ws_size,
                              hipStream_t stream) {
  const float* input  = (const float*)d_in[0];  // (16384, 2048)
  const float* adj    = (const float*)d_in[1];  // (8192, 8192)
  const float* degree = (const float*)d_in[2];  // (16384,)
  const float* W      = (const float*)d_in[3];  // (2048, 2048)
  const float* b      = (const float*)d_in[4];  // (2048,)
  float* out = (float*)d_out;                   // (16384, 2048) fp32

  char* ws = (char*)d_ws;
  bf16* supT   = (bf16*)(ws);                    // 2048 x 16384
  bf16* in_bf  = (bf16*)(ws + (64ULL  << 20));   // 16384 x 2048
  bf16* W_bf   = (bf16*)(ws + (128ULL << 20));   // 2048 x 2048
  bf16* adj_bf = (bf16*)(ws + (64ULL  << 20));   // 8192 x 8192 (reuses in_bf region)
  bf16* adjT   = (bf16*)(ws + (192ULL << 20));   // 8192 x 8192

  // Phase 0: convert GEMM1 operands.
  k_cvt<<<(16384 * 2048 / 4) / 256, 256, 0, stream>>>(input, in_bf);
  k_cvt<<<(2048 * 2048 / 4) / 256, 256, 0, stream>>>(W, W_bf);

  // Phase 1: supT = W @ input^T + b[row].  M=2048, N=16384, K=2048.
  k_gemm_nt<true><<<dim3(16384 / 128, 2048 / 128), 256, 0, stream>>>(
      W_bf, in_bf, supT, 2048, 2048, 2048, 16384, nullptr, b);

  // Phase 2: adj conversions (adj_bf overwrites in_bf -- GEMM1 already done).
  k_cvt<<<(8192 * 8192 / 4) / 256, 256, 0, stream>>>(adj, adj_bf);
  k_transpose_cvt<<<dim3(128, 128), 256, 0, stream>>>(adj, adjT, 8192);

  // Phase 3: out_u = deg_u * (adj @ sup_i).  M=8192, N=2048, K=8192.
  k_gemm_nt<false><<<dim3(2048 / 128, 8192 / 128), 256, 0, stream>>>(
      adj_bf, supT + 8192, out, 8192, 8192, 16384, 2048, degree, nullptr);

  // Phase 4: out_i = deg_i * (adjT @ sup_u).
  k_gemm_nt<false><<<dim3(2048 / 128, 8192 / 128), 256, 0, stream>>>(
      adjT, supT, out + 8192LL * 2048, 8192, 8192, 16384, 2048, degree + 8192, nullptr);
}